// Round 9
// baseline (452.272 us; speedup 1.0000x reference)
//
#include <hip/hip_runtime.h>
#include <cstddef>
#include <cstdint>

#define Bn 4
#define Tn 2048
#define Cn 768
#define Hn 12

typedef __attribute__((ext_vector_type(8))) short short8v;
typedef __attribute__((ext_vector_type(4))) float f32x4;
typedef unsigned short ushort_t;

struct us4 { unsigned short x, y, z, w; };

__device__ inline unsigned short f2bf(float f) {
  union { float f; unsigned u; } v; v.f = f;
  unsigned r = v.u + 0x7FFFu + ((v.u >> 16) & 1u);
  return (unsigned short)(r >> 16);
}
__device__ inline float bf2f(unsigned short u) {
  union { unsigned u; float f; } v; v.u = ((unsigned)u) << 16;
  return v.f;
}
__device__ inline unsigned cvt_pk_bf16(float lo, float hi) {
  unsigned r;
  asm("v_cvt_pk_bf16_f32 %0, %1, %2" : "=v"(r) : "v"(lo), "v"(hi));
  return r;
}
__device__ inline float u2f(unsigned u) {
  union { unsigned u; float f; } v; v.u = u; return v.f;
}

#define GLOAD_LDS16(gp, lp)                                                        \
  __builtin_amdgcn_global_load_lds(                                                \
      (const __attribute__((address_space(1))) void*)(gp),                         \
      (__attribute__((address_space(3))) void*)(lp), 16, 0, 0)

// ---------------- x -> hi/lo bf16 split ----------------
__global__ __launch_bounds__(256) void conv_x_split(const float* __restrict__ in,
                                                    ushort_t* __restrict__ hi,
                                                    ushort_t* __restrict__ lo, int n4) {
  int i = blockIdx.x * 256 + threadIdx.x;
  if (i >= n4) return;
  float4 v = reinterpret_cast<const float4*>(in)[i];
  us4 h, l;
  h.x = f2bf(v.x); l.x = f2bf(v.x - bf2f(h.x));
  h.y = f2bf(v.y); l.y = f2bf(v.y - bf2f(h.y));
  h.z = f2bf(v.z); l.z = f2bf(v.z - bf2f(h.z));
  h.w = f2bf(v.w); l.w = f2bf(v.w - bf2f(h.w));
  reinterpret_cast<us4*>(hi)[i] = h;
  reinterpret_cast<us4*>(lo)[i] = l;
}

// ---------------- W[rows][cols] -> WT[cols][rows] bf16 (optionally hi+lo) --------
template <int SPLIT>
__global__ __launch_bounds__(256) void conv_wT(const float* __restrict__ W,
                                               ushort_t* __restrict__ WTh,
                                               ushort_t* __restrict__ WTl,
                                               int rows, int cols) {
  __shared__ float t[64][65];
  const int r0 = blockIdx.y * 64, c0 = blockIdx.x * 64;
  const int tid = threadIdx.x;
  const int c4 = (tid & 15) << 2;
  #pragma unroll
  for (int rr = 0; rr < 4; ++rr) {
    int r = rr * 16 + (tid >> 4);
    float4 v = *reinterpret_cast<const float4*>(&W[(size_t)(r0 + r) * cols + c0 + c4]);
    t[r][c4] = v.x; t[r][c4 + 1] = v.y; t[r][c4 + 2] = v.z; t[r][c4 + 3] = v.w;
  }
  __syncthreads();
  const int r4 = (tid & 15) << 2;
  #pragma unroll
  for (int cc = 0; cc < 4; ++cc) {
    int c = cc * 16 + (tid >> 4);
    float v0 = t[r4][c], v1 = t[r4 + 1][c], v2 = t[r4 + 2][c], v3 = t[r4 + 3][c];
    us4 h;
    h.x = f2bf(v0); h.y = f2bf(v1); h.z = f2bf(v2); h.w = f2bf(v3);
    *reinterpret_cast<us4*>(&WTh[(size_t)(c0 + c) * rows + r0 + r4]) = h;
    if (SPLIT) {
      us4 l;
      l.x = f2bf(v0 - bf2f(h.x)); l.y = f2bf(v1 - bf2f(h.y));
      l.z = f2bf(v2 - bf2f(h.z)); l.w = f2bf(v3 - bf2f(h.w));
      *reinterpret_cast<us4*>(&WTl[(size_t)(c0 + c) * rows + r0 + r4]) = l;
    }
  }
}

// ---------------- bf16 MFMA GEMM: C = A[M][K] @ Bt[N][K]^T, 128x128, BK=64 -------
// COMP=1: split-bf16 compensated (3-term MFMA, fp32 quality).
// MODE 0: C fp32.  MODE 1: fused qkv epilogue (q,k; v transposed).
// SLICE=1: bm = (y>>1)*Tn + (y&1)*128  (t<256 rows of each batch only).
// WLO=1: also store lo-parts of q,k.
template <int COMP, int MODE, int SLICE, int WLO>
__global__ __launch_bounds__(256) void gemm_bf16(
    const ushort_t* __restrict__ Ah, const ushort_t* __restrict__ Al,
    const ushort_t* __restrict__ Bh, const ushort_t* __restrict__ Bl,
    int M, int N, int K, int bn_off, float* __restrict__ C,
    const float* __restrict__ lambda,
    ushort_t* __restrict__ qhp, ushort_t* __restrict__ qlp,
    ushort_t* __restrict__ khp, ushort_t* __restrict__ klp,
    ushort_t* __restrict__ vtp) {
  __shared__ ushort_t As[COMP + 1][128 * 64];
  __shared__ ushort_t Bs[COMP + 1][128 * 64];

  const int tid = threadIdx.x;
  const int w = tid >> 6;
  const int lane = tid & 63;
  const int lcol = lane & 15;
  const int g = lane >> 4;
  const int bm = SLICE ? ((blockIdx.y >> 1) * Tn + (blockIdx.y & 1) * 128)
                       : (blockIdx.y * 128);
  const int bn = blockIdx.x * 128 + bn_off;
  const int wr = (w >> 1) * 64;
  const int wc = (w & 1) * 64;
  const int srow = tid >> 3;
  const int sslot = tid & 7;

  f32x4 acc[4][4];
  #pragma unroll
  for (int m = 0; m < 4; ++m)
    #pragma unroll
    for (int n = 0; n < 4; ++n)
      acc[m][n] = (f32x4){0.f, 0.f, 0.f, 0.f};

  for (int k0 = 0; k0 < K; k0 += 64) {
    __syncthreads();
    #pragma unroll
    for (int i = 0; i < 4; ++i) {
      const int row = i * 32 + srow;
      const int kslot = sslot ^ (row & 7);
      const size_t ga = (size_t)(bm + row) * K + k0 + kslot * 8;
      const size_t gb = (size_t)(bn + row) * K + k0 + kslot * 8;
      const size_t ldst = (size_t)(i * 256 + tid) * 16;
      GLOAD_LDS16(Ah + ga, (char*)As[0] + ldst);
      GLOAD_LDS16(Bh + gb, (char*)Bs[0] + ldst);
      if (COMP) {
        GLOAD_LDS16(Al + ga, (char*)As[COMP] + ldst);
        GLOAD_LDS16(Bl + gb, (char*)Bs[COMP] + ldst);
      }
    }
    __syncthreads();
    #pragma unroll
    for (int kk = 0; kk < 2; ++kk) {
      short8v a0[4], b0[4], a1[4], b1[4];
      #pragma unroll
      for (int m = 0; m < 4; ++m) {
        int row = wr + m * 16 + lcol;
        int off = row * 128 + (((kk * 4 + g) ^ (row & 7)) << 4);
        a0[m] = *reinterpret_cast<const short8v*>((const char*)As[0] + off);
        if (COMP) a1[m] = *reinterpret_cast<const short8v*>((const char*)As[COMP] + off);
      }
      #pragma unroll
      for (int n = 0; n < 4; ++n) {
        int row = wc + n * 16 + lcol;
        int off = row * 128 + (((kk * 4 + g) ^ (row & 7)) << 4);
        b0[n] = *reinterpret_cast<const short8v*>((const char*)Bs[0] + off);
        if (COMP) b1[n] = *reinterpret_cast<const short8v*>((const char*)Bs[COMP] + off);
      }
      #pragma unroll
      for (int m = 0; m < 4; ++m)
        #pragma unroll
        for (int n = 0; n < 4; ++n) {
          acc[m][n] = __builtin_amdgcn_mfma_f32_16x16x32_bf16(a0[m], b0[n], acc[m][n], 0, 0, 0);
          if (COMP) {
            acc[m][n] = __builtin_amdgcn_mfma_f32_16x16x32_bf16(a0[m], b1[n], acc[m][n], 0, 0, 0);
            acc[m][n] = __builtin_amdgcn_mfma_f32_16x16x32_bf16(a1[m], b0[n], acc[m][n], 0, 0, 0);
          }
        }
    }
  }

  if (MODE == 0) {
    #pragma unroll
    for (int m = 0; m < 4; ++m) {
      const int rowm = bm + wr + m * 16 + g * 4;
      #pragma unroll
      for (int n = 0; n < 4; ++n) {
        const int col = bn + wc + n * 16 + lcol;
        #pragma unroll
        for (int j = 0; j < 4; ++j)
          C[(size_t)(rowm + j) * N + col] = acc[m][n][j];
      }
    }
  } else {
    const int seg = bn / Cn;                  // uniform (768 % 128 == 0)
    const int nloc_base = bn - seg * Cn + wc;
    #pragma unroll
    for (int m = 0; m < 4; ++m) {
      const int mg = bm + wr + m * 16 + g * 4;
      const int bidx = mg >> 11;
      const int tbase = mg & (Tn - 1);
      float lgt[4];
      if (seg == 0) {
        #pragma unroll
        for (int j = 0; j < 4; ++j) lgt[j] = logf((float)(tbase + j) + 1.0f);
      }
      #pragma unroll
      for (int n = 0; n < 4; ++n) {
        const int nloc = nloc_base + n * 16 + lcol;
        const int h = nloc >> 6;
        const int d = nloc & 63;
        const size_t bhh = (size_t)(bidx * Hn + h);
        if (seg == 0) {
          const float lam = lambda[h];
          #pragma unroll
          for (int j = 0; j < 4; ++j) {
            float val = acc[m][n][j] * (0.125f * (1.0f + lam * lgt[j]));
            unsigned short hi = f2bf(val);
            size_t idx = (bhh * Tn + tbase + j) * 64 + d;
            qhp[idx] = hi;
            if (WLO) qlp[idx] = f2bf(val - bf2f(hi));
          }
        } else if (seg == 1) {
          #pragma unroll
          for (int j = 0; j < 4; ++j) {
            float val = acc[m][n][j];
            unsigned short hi = f2bf(val);
            size_t idx = (bhh * Tn + tbase + j) * 64 + d;
            khp[idx] = hi;
            if (WLO) klp[idx] = f2bf(val - bf2f(hi));
          }
        } else {
          #pragma unroll
          for (int j = 0; j < 4; ++j)
            vtp[(bhh * 64 + d) * Tn + tbase + j] = f2bf(acc[m][n][j]);
        }
      }
    }
  }
}

// ---------------- MFMA flash-style relu-attention, 128 q-rows/block --------------
// 2-phase double-buffered K/V staging; LDS exactly 40 KB -> 4 blocks/CU.
// Precision scoping: qt==0 q+k comp; qt==1 q comp; qt>=2 plain.
__global__ __launch_bounds__(256, 4) void attn_mfma(
    const ushort_t* __restrict__ qh, const ushort_t* __restrict__ ql,
    const ushort_t* __restrict__ kh, const ushort_t* __restrict__ kl,
    const ushort_t* __restrict__ vt, const float* __restrict__ attn_mask,
    ushort_t* __restrict__ ao) {
  static const int QT1[16] = {15,13,11,9,7,5,3,1,14,12,10,8,6,4,2,0};
  static const int QT2[16] = {7,9,10,11,12,13,14,15,0,1,2,3,4,5,6,8};
  const int cc_ = blockIdx.x & 255;
  const int rr_ = blockIdx.x >> 8;           // 0..2
  const int bh  = (cc_ >> 4) + (rr_ << 4);   // 0..47
  const int ii_ = cc_ & 15;
  const int qt  = (rr_ == 0) ? ii_ : (rr_ == 1 ? QT1[ii_] : QT2[ii_]);
  const int b = bh / Hn, h = bh % Hn;
  const int tid = threadIdx.x;
  const int w = tid >> 6, lane = tid & 63, lcol = lane & 15, g = lane >> 4;

  const bool compq = (qt <= 1);

  __shared__ ushort_t Kh_lds[2][64 * 64];   // 16 KB (buffer 1 doubles as Kl for qt==0)
  __shared__ ushort_t V_lds[2][64 * 64];    // 16 KB
  __shared__ ushort_t P_lds[4][16 * 64];    // 8 KB, per-wave, single m-group, XOR-swz

  // Q hi fragments for the wave's two 16-row groups
  short8v qfh[2][2];
  #pragma unroll
  for (int m = 0; m < 2; ++m) {
    const size_t qoff = ((size_t)bh * Tn + qt * 128 + w * 32 + m * 16 + lcol) * 64;
    qfh[m][0] = *reinterpret_cast<const short8v*>(qh + qoff + g * 8);
    qfh[m][1] = *reinterpret_cast<const short8v*>(qh + qoff + 32 + g * 8);
  }

  f32x4 o[2][4];
  float dsum[2][4];
  #pragma unroll
  for (int m = 0; m < 2; ++m) {
    #pragma unroll
    for (int dt = 0; dt < 4; ++dt) o[m][dt] = (f32x4){0.f, 0.f, 0.f, 0.f};
    #pragma unroll
    for (int r = 0; r < 4; ++r) dsum[m][r] = 0.f;
  }

  float mv_cur[4], mv_nxt[4];

  auto STAGE = [&](int kt, int d) {
    const ushort_t* ks = kh + ((size_t)bh * Tn + kt * 64) * 64;
    const ushort_t* vs = vt + (size_t)bh * 64 * Tn + kt * 64;
    #pragma unroll
    for (int it = 0; it < 2; ++it) {
      const int s = it * 256 + tid;
      const int row = s >> 3, sslot = s & 7;
      const int swz = (sslot ^ (row & 7)) * 8;
      GLOAD_LDS16(ks + row * 64 + swz, (char*)Kh_lds[d] + (size_t)s * 16);
      GLOAD_LDS16(vs + (size_t)row * Tn + swz, (char*)V_lds[d] + (size_t)s * 16);
    }
  };
  auto STAGE_KL = [&](int kt) {   // qt==0 only: Kl parked in Kh_lds[1]
    const ushort_t* ls = kl + ((size_t)bh * Tn + kt * 64) * 64;
    #pragma unroll
    for (int it = 0; it < 2; ++it) {
      const int s = it * 256 + tid;
      const int row = s >> 3, sslot = s & 7;
      const int swz = (sslot ^ (row & 7)) * 8;
      GLOAD_LDS16(ls + row * 64 + swz, (char*)Kh_lds[1] + (size_t)s * 16);
    }
  };
  auto MLOAD = [&](int kt, float* mv) {
    #pragma unroll
    for (int c = 0; c < 4; ++c)
      mv[c] = attn_mask[b * Tn + kt * 64 + c * 16 + lcol];
  };

  // P byte offset with XOR swizzle (row-major [16][64] bf16, 128B rows)
  auto PBYTE = [](int row, int col2) { return row * 128 + (col2 ^ ((row & 7) << 4)); };

  auto COMPUTE = [&](int kt, int d, bool cq, bool ck) {
    // V fragments for this tile, cached in regs (shared by both m-groups)
    short8v vf[4][2];
    #pragma unroll
    for (int dt = 0; dt < 4; ++dt) {
      const int vrow = dt * 16 + lcol;
      const int vro = vrow * 128;
      vf[dt][0] = *reinterpret_cast<const short8v*>(
          (const char*)V_lds[d] + vro + ((g ^ (vrow & 7)) << 4));
      vf[dt][1] = *reinterpret_cast<const short8v*>(
          (const char*)V_lds[d] + vro + (((4 + g) ^ (vrow & 7)) << 4));
    }
    #pragma unroll
    for (int m = 0; m < 2; ++m) {
      const int qg = qt * 128 + w * 32 + m * 16;
      if (kt * 64 > qg + 15) continue;
      const bool diag = (kt * 64 + 63 > qg);
      short8v qfl0, qfl1;
      if (cq) {
        const size_t qoff = ((size_t)bh * Tn + qg + lcol) * 64;
        qfl0 = *reinterpret_cast<const short8v*>(ql + qoff + g * 8);
        qfl1 = *reinterpret_cast<const short8v*>(ql + qoff + 32 + g * 8);
      }
      #pragma unroll
      for (int c = 0; c < 4; ++c) {
        const int row = c * 16 + lcol;
        const int roff = row * 128;
        const int s0 = (g ^ (row & 7)) << 4;
        const int s1 = ((4 + g) ^ (row & 7)) << 4;
        short8v kf0 = *reinterpret_cast<const short8v*>((const char*)Kh_lds[d] + roff + s0);
        short8v kf1 = *reinterpret_cast<const short8v*>((const char*)Kh_lds[d] + roff + s1);
        f32x4 s = (f32x4){0.f, 0.f, 0.f, 0.f};
        __builtin_amdgcn_s_setprio(1);
        s = __builtin_amdgcn_mfma_f32_16x16x32_bf16(qfh[m][0], kf0, s, 0, 0, 0);
        s = __builtin_amdgcn_mfma_f32_16x16x32_bf16(qfh[m][1], kf1, s, 0, 0, 0);
        if (cq) {
          s = __builtin_amdgcn_mfma_f32_16x16x32_bf16(qfl0, kf0, s, 0, 0, 0);
          s = __builtin_amdgcn_mfma_f32_16x16x32_bf16(qfl1, kf1, s, 0, 0, 0);
        }
        if (ck) {
          short8v kl0 = *reinterpret_cast<const short8v*>((const char*)Kh_lds[1] + roff + s0);
          short8v kl1 = *reinterpret_cast<const short8v*>((const char*)Kh_lds[1] + roff + s1);
          s = __builtin_amdgcn_mfma_f32_16x16x32_bf16(qfh[m][0], kl0, s, 0, 0, 0);
          s = __builtin_amdgcn_mfma_f32_16x16x32_bf16(qfh[m][1], kl1, s, 0, 0, 0);
        }
        __builtin_amdgcn_s_setprio(0);
        const float mval = mv_cur[c];
        float sv[4];
        #pragma unroll
        for (int r = 0; r < 4; ++r) {
          float v = fmaxf(s[r], 0.f) * mval;
          if (diag) {
            const int kr = kt * 64 + row;
            const int qr = qg + g * 4 + r;
            v = (kr <= qr) ? v : 0.f;
          }
          sv[r] = v;
        }
        const unsigned p01 = cvt_pk_bf16(sv[0], sv[1]);
        const unsigned p23 = cvt_pk_bf16(sv[2], sv[3]);
        char* pb = (char*)P_lds[w];
        const int col2 = row * 2;   // k-col byte offset within P row
        *(ushort_t*)(pb + PBYTE(g * 4 + 0, col2)) = (ushort_t)p01;
        *(ushort_t*)(pb + PBYTE(g * 4 + 1, col2)) = (ushort_t)(p01 >> 16);
        *(ushort_t*)(pb + PBYTE(g * 4 + 2, col2)) = (ushort_t)p23;
        *(ushort_t*)(pb + PBYTE(g * 4 + 3, col2)) = (ushort_t)(p23 >> 16);
        dsum[m][0] += u2f(p01 << 16);
        dsum[m][1] += u2f(p01 & 0xFFFF0000u);
        dsum[m][2] += u2f(p23 << 16);
        dsum[m][3] += u2f(p23 & 0xFFFF0000u);
      }
      // PV for this m-group (same-wave LDS ordering makes this safe)
      short8v pf0 = *reinterpret_cast<const short8v*>(
          (const char*)P_lds[w] + PBYTE(lcol, g * 16));
      short8v pf1 = *reinterpret_cast<const short8v*>(
          (const char*)P_lds[w] + PBYTE(lcol, 64 + g * 16));
      __builtin_amdgcn_s_setprio(1);
      #pragma unroll
      for (int dt = 0; dt < 4; ++dt) {
        o[m][dt] = __builtin_amdgcn_mfma_f32_16x16x32_bf16(pf0, vf[dt][0], o[m][dt], 0, 0, 0);
        o[m][dt] = __builtin_amdgcn_mfma_f32_16x16x32_bf16(pf1, vf[dt][1], o[m][dt], 0, 0, 0);
      }
      __builtin_amdgcn_s_setprio(0);
    }
  };

  if (qt == 0) {
    for (int kt = 0; kt < 2; ++kt) {
      STAGE(kt, 0);
      STAGE_KL(kt);
      MLOAD(kt, mv_cur);
      __syncthreads();
      COMPUTE(kt, 0, true, true);
      __syncthreads();
    }
  } else {
    const int ntiles = 2 * qt + 2;
    MLOAD(0, mv_cur);
    STAGE(0, 0);
    __syncthreads();
    for (int kt = 0; kt < ntiles; ++kt) {
      const int d = kt & 1;
      if (kt + 1 < ntiles) { STAGE(kt + 1, d ^ 1); MLOAD(kt + 1, mv_nxt); }
      COMPUTE(kt, d, compq, false);
      __syncthreads();
      #pragma unroll
      for (int c = 0; c < 4; ++c) mv_cur[c] = mv_nxt[c];
    }
  }

  #pragma unroll
  for (int m = 0; m < 2; ++m) {
    float inv[4];
    #pragma unroll
    for (int r = 0; r < 4; ++r) {
      float d = dsum[m][r];
      d += __shfl_xor(d, 1); d += __shfl_xor(d, 2);
      d += __shfl_xor(d, 4); d += __shfl_xor(d, 8);
      inv[r] = 1.0f / (d + 1e-9f);
    }
    ushort_t* ob = ao + ((size_t)b * Tn + qt * 128 + w * 32 + m * 16) * Cn + h * 64;
    #pragma unroll
    for (int dt = 0; dt < 4; ++dt)
      #pragma unroll
      for (int r = 0; r < 4; ++r)
        ob[(size_t)(g * 4 + r) * Cn + dt * 16 + lcol] = f2bf(o[m][dt][r] * inv[r]);
  }
}

extern "C" void kernel_launch(void* const* d_in, const int* in_sizes, int n_in,
                              void* d_out, int out_size, void* d_ws, size_t ws_size,
                              hipStream_t stream) {
  const float* x         = (const float*)d_in[0];
  const float* attn_mask = (const float*)d_in[1];
  const float* lambda    = (const float*)d_in[2];
  const float* W_attn    = (const float*)d_in[3];
  const float* W_proj    = (const float*)d_in[4];
  float* out = (float*)d_out;

  const size_t nBTC = (size_t)Bn * Tn * Cn;        // 6.29M
  const size_t nW1  = (size_t)Cn * 3 * Cn;         // 1.77M
  const size_t nW2  = (size_t)Cn * Cn;             // 0.59M
  ushort_t* xh  = (ushort_t*)d_ws;
  ushort_t* xl  = xh + nBTC;
  ushort_t* WhT = xl + nBTC;
  ushort_t* WlT = WhT + nW1;
  ushort_t* WpT = WlT + nW1;
  ushort_t* qh  = WpT + nW2;
  ushort_t* ql  = qh + nBTC;
  ushort_t* kh  = ql + nBTC;
  ushort_t* kl  = kh + nBTC;
  ushort_t* vt  = kl + nBTC;
  ushort_t* ao  = xh;   // xh dead after gemm1; reuse for attention output

  dim3 blk(256);

  conv_x_split<<<dim3((unsigned)(nBTC / 4 / 256)), blk, 0, stream>>>(
      x, xh, xl, (int)(nBTC / 4));
  conv_wT<1><<<dim3(36, 12), blk, 0, stream>>>(W_attn, WhT, WlT, Cn, 3 * Cn);
  conv_wT<0><<<dim3(12, 12), blk, 0, stream>>>(W_proj, WpT, nullptr, Cn, Cn);

  // full qkv: plain bf16 GEMM (hi only; v transposed)
  gemm_bf16<0, 1, 0, 0><<<dim3(18, 64), blk, 0, stream>>>(
      xh, nullptr, WhT, nullptr, Bn * Tn, 3 * Cn, Cn, 0, nullptr, lambda,
      qh, ql, kh, kl, vt);
  // accurate overwrite slice: rows t<256 of q,k (compensated, writes hi+lo)
  gemm_bf16<1, 1, 1, 1><<<dim3(12, 8), blk, 0, stream>>>(
      xh, xl, WhT, WlT, Bn * Tn, 3 * Cn, Cn, 0, nullptr, lambda,
      qh, ql, kh, kl, vt);

  attn_mfma<<<dim3(768), blk, 0, stream>>>(
      qh, ql, kh, kl, vt, attn_mask, ao);

  gemm_bf16<0, 0, 0, 0><<<dim3(6, 64), blk, 0, stream>>>(
      ao, nullptr, WpT, nullptr, Bn * Tn, Cn, Cn, 0, out, nullptr,
      nullptr, nullptr, nullptr, nullptr, nullptr);
}

// Round 10
// 198.834 us; speedup vs baseline: 2.2746x; 2.2746x over previous
//
#include <hip/hip_runtime.h>
#include <cstddef>
#include <cstdint>

#define Bn 4
#define Tn 2048
#define Cn 768
#define Hn 12

typedef __attribute__((ext_vector_type(8))) short short8v;
typedef __attribute__((ext_vector_type(4))) float f32x4;
typedef unsigned short ushort_t;

struct us4 { unsigned short x, y, z, w; };

__device__ inline unsigned short f2bf(float f) {
  union { float f; unsigned u; } v; v.f = f;
  unsigned r = v.u + 0x7FFFu + ((v.u >> 16) & 1u);
  return (unsigned short)(r >> 16);
}
__device__ inline float bf2f(unsigned short u) {
  union { unsigned u; float f; } v; v.u = ((unsigned)u) << 16;
  return v.f;
}
__device__ inline unsigned cvt_pk_bf16(float lo, float hi) {
  unsigned r;
  asm("v_cvt_pk_bf16_f32 %0, %1, %2" : "=v"(r) : "v"(lo), "v"(hi));
  return r;
}
__device__ inline float u2f(unsigned u) {
  union { unsigned u; float f; } v; v.u = u; return v.f;
}

#define GLOAD_LDS16(gp, lp)                                                        \
  __builtin_amdgcn_global_load_lds(                                                \
      (const __attribute__((address_space(1))) void*)(gp),                         \
      (__attribute__((address_space(3))) void*)(lp), 16, 0, 0)

// ---------------- x -> hi/lo bf16 split ----------------
__global__ __launch_bounds__(256) void conv_x_split(const float* __restrict__ in,
                                                    ushort_t* __restrict__ hi,
                                                    ushort_t* __restrict__ lo, int n4) {
  int i = blockIdx.x * 256 + threadIdx.x;
  if (i >= n4) return;
  float4 v = reinterpret_cast<const float4*>(in)[i];
  us4 h, l;
  h.x = f2bf(v.x); l.x = f2bf(v.x - bf2f(h.x));
  h.y = f2bf(v.y); l.y = f2bf(v.y - bf2f(h.y));
  h.z = f2bf(v.z); l.z = f2bf(v.z - bf2f(h.z));
  h.w = f2bf(v.w); l.w = f2bf(v.w - bf2f(h.w));
  reinterpret_cast<us4*>(hi)[i] = h;
  reinterpret_cast<us4*>(lo)[i] = l;
}

// ---------------- W[rows][cols] -> WT[cols][rows] bf16 (optionally hi+lo) --------
template <int SPLIT>
__global__ __launch_bounds__(256) void conv_wT(const float* __restrict__ W,
                                               ushort_t* __restrict__ WTh,
                                               ushort_t* __restrict__ WTl,
                                               int rows, int cols) {
  __shared__ float t[64][65];
  const int r0 = blockIdx.y * 64, c0 = blockIdx.x * 64;
  const int tid = threadIdx.x;
  const int c4 = (tid & 15) << 2;
  #pragma unroll
  for (int rr = 0; rr < 4; ++rr) {
    int r = rr * 16 + (tid >> 4);
    float4 v = *reinterpret_cast<const float4*>(&W[(size_t)(r0 + r) * cols + c0 + c4]);
    t[r][c4] = v.x; t[r][c4 + 1] = v.y; t[r][c4 + 2] = v.z; t[r][c4 + 3] = v.w;
  }
  __syncthreads();
  const int r4 = (tid & 15) << 2;
  #pragma unroll
  for (int cc = 0; cc < 4; ++cc) {
    int c = cc * 16 + (tid >> 4);
    float v0 = t[r4][c], v1 = t[r4 + 1][c], v2 = t[r4 + 2][c], v3 = t[r4 + 3][c];
    us4 h;
    h.x = f2bf(v0); h.y = f2bf(v1); h.z = f2bf(v2); h.w = f2bf(v3);
    *reinterpret_cast<us4*>(&WTh[(size_t)(c0 + c) * rows + r0 + r4]) = h;
    if (SPLIT) {
      us4 l;
      l.x = f2bf(v0 - bf2f(h.x)); l.y = f2bf(v1 - bf2f(h.y));
      l.z = f2bf(v2 - bf2f(h.z)); l.w = f2bf(v3 - bf2f(h.w));
      *reinterpret_cast<us4*>(&WTl[(size_t)(c0 + c) * rows + r0 + r4]) = l;
    }
  }
}

// ---------------- bf16 MFMA GEMM: C = A[M][K] @ Bt[N][K]^T, 128x128, BK=64 -------
// COMP=1: split-bf16 compensated (3-term MFMA, fp32 quality).
// MODE 0: C fp32.  MODE 1: fused qkv epilogue (q,k; v transposed).
// SLICE=1: bm = (y>>1)*Tn + (y&1)*128  (t<256 rows of each batch only).
// WLO=1: also store lo-parts of q,k.
template <int COMP, int MODE, int SLICE, int WLO>
__global__ __launch_bounds__(256) void gemm_bf16(
    const ushort_t* __restrict__ Ah, const ushort_t* __restrict__ Al,
    const ushort_t* __restrict__ Bh, const ushort_t* __restrict__ Bl,
    int M, int N, int K, int bn_off, float* __restrict__ C,
    const float* __restrict__ lambda,
    ushort_t* __restrict__ qhp, ushort_t* __restrict__ qlp,
    ushort_t* __restrict__ khp, ushort_t* __restrict__ klp,
    ushort_t* __restrict__ vtp) {
  __shared__ ushort_t As[COMP + 1][128 * 64];
  __shared__ ushort_t Bs[COMP + 1][128 * 64];

  const int tid = threadIdx.x;
  const int w = tid >> 6;
  const int lane = tid & 63;
  const int lcol = lane & 15;
  const int g = lane >> 4;
  const int bm = SLICE ? ((blockIdx.y >> 1) * Tn + (blockIdx.y & 1) * 128)
                       : (blockIdx.y * 128);
  const int bn = blockIdx.x * 128 + bn_off;
  const int wr = (w >> 1) * 64;
  const int wc = (w & 1) * 64;
  const int srow = tid >> 3;
  const int sslot = tid & 7;

  f32x4 acc[4][4];
  #pragma unroll
  for (int m = 0; m < 4; ++m)
    #pragma unroll
    for (int n = 0; n < 4; ++n)
      acc[m][n] = (f32x4){0.f, 0.f, 0.f, 0.f};

  for (int k0 = 0; k0 < K; k0 += 64) {
    __syncthreads();
    #pragma unroll
    for (int i = 0; i < 4; ++i) {
      const int row = i * 32 + srow;
      const int kslot = sslot ^ (row & 7);
      const size_t ga = (size_t)(bm + row) * K + k0 + kslot * 8;
      const size_t gb = (size_t)(bn + row) * K + k0 + kslot * 8;
      const size_t ldst = (size_t)(i * 256 + tid) * 16;
      GLOAD_LDS16(Ah + ga, (char*)As[0] + ldst);
      GLOAD_LDS16(Bh + gb, (char*)Bs[0] + ldst);
      if (COMP) {
        GLOAD_LDS16(Al + ga, (char*)As[COMP] + ldst);
        GLOAD_LDS16(Bl + gb, (char*)Bs[COMP] + ldst);
      }
    }
    __syncthreads();
    #pragma unroll
    for (int kk = 0; kk < 2; ++kk) {
      short8v a0[4], b0[4], a1[4], b1[4];
      #pragma unroll
      for (int m = 0; m < 4; ++m) {
        int row = wr + m * 16 + lcol;
        int off = row * 128 + (((kk * 4 + g) ^ (row & 7)) << 4);
        a0[m] = *reinterpret_cast<const short8v*>((const char*)As[0] + off);
        if (COMP) a1[m] = *reinterpret_cast<const short8v*>((const char*)As[COMP] + off);
      }
      #pragma unroll
      for (int n = 0; n < 4; ++n) {
        int row = wc + n * 16 + lcol;
        int off = row * 128 + (((kk * 4 + g) ^ (row & 7)) << 4);
        b0[n] = *reinterpret_cast<const short8v*>((const char*)Bs[0] + off);
        if (COMP) b1[n] = *reinterpret_cast<const short8v*>((const char*)Bs[COMP] + off);
      }
      #pragma unroll
      for (int m = 0; m < 4; ++m)
        #pragma unroll
        for (int n = 0; n < 4; ++n) {
          acc[m][n] = __builtin_amdgcn_mfma_f32_16x16x32_bf16(a0[m], b0[n], acc[m][n], 0, 0, 0);
          if (COMP) {
            acc[m][n] = __builtin_amdgcn_mfma_f32_16x16x32_bf16(a0[m], b1[n], acc[m][n], 0, 0, 0);
            acc[m][n] = __builtin_amdgcn_mfma_f32_16x16x32_bf16(a1[m], b0[n], acc[m][n], 0, 0, 0);
          }
        }
    }
  }

  if (MODE == 0) {
    #pragma unroll
    for (int m = 0; m < 4; ++m) {
      const int rowm = bm + wr + m * 16 + g * 4;
      #pragma unroll
      for (int n = 0; n < 4; ++n) {
        const int col = bn + wc + n * 16 + lcol;
        #pragma unroll
        for (int j = 0; j < 4; ++j)
          C[(size_t)(rowm + j) * N + col] = acc[m][n][j];
      }
    }
  } else {
    const int seg = bn / Cn;                  // uniform (768 % 128 == 0)
    const int nloc_base = bn - seg * Cn + wc;
    #pragma unroll
    for (int m = 0; m < 4; ++m) {
      const int mg = bm + wr + m * 16 + g * 4;
      const int bidx = mg >> 11;
      const int tbase = mg & (Tn - 1);
      float lgt[4];
      if (seg == 0) {
        #pragma unroll
        for (int j = 0; j < 4; ++j) lgt[j] = logf((float)(tbase + j) + 1.0f);
      }
      #pragma unroll
      for (int n = 0; n < 4; ++n) {
        const int nloc = nloc_base + n * 16 + lcol;
        const int h = nloc >> 6;
        const int d = nloc & 63;
        const size_t bhh = (size_t)(bidx * Hn + h);
        if (seg == 0) {
          const float lam = lambda[h];
          #pragma unroll
          for (int j = 0; j < 4; ++j) {
            float val = acc[m][n][j] * (0.125f * (1.0f + lam * lgt[j]));
            unsigned short hi = f2bf(val);
            size_t idx = (bhh * Tn + tbase + j) * 64 + d;
            qhp[idx] = hi;
            if (WLO) qlp[idx] = f2bf(val - bf2f(hi));
          }
        } else if (seg == 1) {
          #pragma unroll
          for (int j = 0; j < 4; ++j) {
            float val = acc[m][n][j];
            unsigned short hi = f2bf(val);
            size_t idx = (bhh * Tn + tbase + j) * 64 + d;
            khp[idx] = hi;
            if (WLO) klp[idx] = f2bf(val - bf2f(hi));
          }
        } else {
          #pragma unroll
          for (int j = 0; j < 4; ++j)
            vtp[(bhh * 64 + d) * Tn + tbase + j] = f2bf(acc[m][n][j]);
        }
      }
    }
  }
}

// ---------------- MFMA flash-style relu-attention, 128 q-rows/block --------------
// 2-phase double-buffered K/V staging; LDS exactly 40 KB (4 blocks/CU if VGPR<=128).
// NO launch_bounds min-wave arg (round 9 lesson: it forced 64 VGPR -> scratch spills).
// Precision scoping: qt==0 q+k comp; qt==1 q comp; qt>=2 plain.
__global__ __launch_bounds__(256) void attn_mfma(
    const ushort_t* __restrict__ qh, const ushort_t* __restrict__ ql,
    const ushort_t* __restrict__ kh, const ushort_t* __restrict__ kl,
    const ushort_t* __restrict__ vt, const float* __restrict__ attn_mask,
    ushort_t* __restrict__ ao) {
  static const int QT1[16] = {15,13,11,9,7,5,3,1,14,12,10,8,6,4,2,0};
  static const int QT2[16] = {7,9,10,11,12,13,14,15,0,1,2,3,4,5,6,8};
  const int cc_ = blockIdx.x & 255;
  const int rr_ = blockIdx.x >> 8;           // 0..2
  const int bh  = (cc_ >> 4) + (rr_ << 4);   // 0..47
  const int ii_ = cc_ & 15;
  const int qt  = (rr_ == 0) ? ii_ : (rr_ == 1 ? QT1[ii_] : QT2[ii_]);
  const int b = bh / Hn, h = bh % Hn;
  const int tid = threadIdx.x;
  const int w = tid >> 6, lane = tid & 63, lcol = lane & 15, g = lane >> 4;

  const bool compq = (qt <= 1);

  __shared__ ushort_t Kh_lds[2][64 * 64];   // 16 KB (buffer 1 doubles as Kl for qt==0)
  __shared__ ushort_t V_lds[2][64 * 64];    // 16 KB
  __shared__ ushort_t P_lds[4][16 * 64];    // 8 KB, per-wave, single m-group, XOR-swz

  // Q hi fragments for the wave's two 16-row groups
  short8v qfh[2][2];
  #pragma unroll
  for (int m = 0; m < 2; ++m) {
    const size_t qoff = ((size_t)bh * Tn + qt * 128 + w * 32 + m * 16 + lcol) * 64;
    qfh[m][0] = *reinterpret_cast<const short8v*>(qh + qoff + g * 8);
    qfh[m][1] = *reinterpret_cast<const short8v*>(qh + qoff + 32 + g * 8);
  }

  f32x4 o[2][4];
  float dsum[2][4];
  #pragma unroll
  for (int m = 0; m < 2; ++m) {
    #pragma unroll
    for (int dt = 0; dt < 4; ++dt) o[m][dt] = (f32x4){0.f, 0.f, 0.f, 0.f};
    #pragma unroll
    for (int r = 0; r < 4; ++r) dsum[m][r] = 0.f;
  }

  float mv_cur[4], mv_nxt[4];

  auto STAGE = [&](int kt, int d) {
    const ushort_t* ks = kh + ((size_t)bh * Tn + kt * 64) * 64;
    const ushort_t* vs = vt + (size_t)bh * 64 * Tn + kt * 64;
    #pragma unroll
    for (int it = 0; it < 2; ++it) {
      const int s = it * 256 + tid;
      const int row = s >> 3, sslot = s & 7;
      const int swz = (sslot ^ (row & 7)) * 8;
      GLOAD_LDS16(ks + row * 64 + swz, (char*)Kh_lds[d] + (size_t)s * 16);
      GLOAD_LDS16(vs + (size_t)row * Tn + swz, (char*)V_lds[d] + (size_t)s * 16);
    }
  };
  auto STAGE_KL = [&](int kt) {   // qt==0 only: Kl parked in Kh_lds[1]
    const ushort_t* ls = kl + ((size_t)bh * Tn + kt * 64) * 64;
    #pragma unroll
    for (int it = 0; it < 2; ++it) {
      const int s = it * 256 + tid;
      const int row = s >> 3, sslot = s & 7;
      const int swz = (sslot ^ (row & 7)) * 8;
      GLOAD_LDS16(ls + row * 64 + swz, (char*)Kh_lds[1] + (size_t)s * 16);
    }
  };
  auto MLOAD = [&](int kt, float* mv) {
    #pragma unroll
    for (int c = 0; c < 4; ++c)
      mv[c] = attn_mask[b * Tn + kt * 64 + c * 16 + lcol];
  };

  // P byte offset with XOR swizzle (row-major [16][64] bf16, 128B rows)
  auto PBYTE = [](int row, int col2) { return row * 128 + (col2 ^ ((row & 7) << 4)); };

  auto COMPUTE = [&](int kt, int d, bool cq, bool ck) {
    #pragma unroll
    for (int m = 0; m < 2; ++m) {
      const int qg = qt * 128 + w * 32 + m * 16;
      if (kt * 64 > qg + 15) continue;
      const bool diag = (kt * 64 + 63 > qg);
      short8v qfl0, qfl1;
      if (cq) {
        const size_t qoff = ((size_t)bh * Tn + qg + lcol) * 64;
        qfl0 = *reinterpret_cast<const short8v*>(ql + qoff + g * 8);
        qfl1 = *reinterpret_cast<const short8v*>(ql + qoff + 32 + g * 8);
      }
      #pragma unroll
      for (int c = 0; c < 4; ++c) {
        const int row = c * 16 + lcol;
        const int roff = row * 128;
        const int s0 = (g ^ (row & 7)) << 4;
        const int s1 = ((4 + g) ^ (row & 7)) << 4;
        short8v kf0 = *reinterpret_cast<const short8v*>((const char*)Kh_lds[d] + roff + s0);
        short8v kf1 = *reinterpret_cast<const short8v*>((const char*)Kh_lds[d] + roff + s1);
        f32x4 s = (f32x4){0.f, 0.f, 0.f, 0.f};
        __builtin_amdgcn_s_setprio(1);
        s = __builtin_amdgcn_mfma_f32_16x16x32_bf16(qfh[m][0], kf0, s, 0, 0, 0);
        s = __builtin_amdgcn_mfma_f32_16x16x32_bf16(qfh[m][1], kf1, s, 0, 0, 0);
        if (cq) {
          s = __builtin_amdgcn_mfma_f32_16x16x32_bf16(qfl0, kf0, s, 0, 0, 0);
          s = __builtin_amdgcn_mfma_f32_16x16x32_bf16(qfl1, kf1, s, 0, 0, 0);
        }
        if (ck) {
          short8v kl0 = *reinterpret_cast<const short8v*>((const char*)Kh_lds[1] + roff + s0);
          short8v kl1 = *reinterpret_cast<const short8v*>((const char*)Kh_lds[1] + roff + s1);
          s = __builtin_amdgcn_mfma_f32_16x16x32_bf16(qfh[m][0], kl0, s, 0, 0, 0);
          s = __builtin_amdgcn_mfma_f32_16x16x32_bf16(qfh[m][1], kl1, s, 0, 0, 0);
        }
        __builtin_amdgcn_s_setprio(0);
        const float mval = mv_cur[c];
        float sv[4];
        #pragma unroll
        for (int r = 0; r < 4; ++r) {
          float v = fmaxf(s[r], 0.f) * mval;
          if (diag) {
            const int kr = kt * 64 + row;
            const int qr = qg + g * 4 + r;
            v = (kr <= qr) ? v : 0.f;
          }
          sv[r] = v;
        }
        const unsigned p01 = cvt_pk_bf16(sv[0], sv[1]);
        const unsigned p23 = cvt_pk_bf16(sv[2], sv[3]);
        char* pb = (char*)P_lds[w];
        const int col2 = row * 2;   // k-col byte offset within P row
        *(ushort_t*)(pb + PBYTE(g * 4 + 0, col2)) = (ushort_t)p01;
        *(ushort_t*)(pb + PBYTE(g * 4 + 1, col2)) = (ushort_t)(p01 >> 16);
        *(ushort_t*)(pb + PBYTE(g * 4 + 2, col2)) = (ushort_t)p23;
        *(ushort_t*)(pb + PBYTE(g * 4 + 3, col2)) = (ushort_t)(p23 >> 16);
        dsum[m][0] += u2f(p01 << 16);
        dsum[m][1] += u2f(p01 & 0xFFFF0000u);
        dsum[m][2] += u2f(p23 << 16);
        dsum[m][3] += u2f(p23 & 0xFFFF0000u);
      }
      // PV for this m-group (same-wave LDS ordering makes this safe)
      short8v pf0 = *reinterpret_cast<const short8v*>(
          (const char*)P_lds[w] + PBYTE(lcol, g * 16));
      short8v pf1 = *reinterpret_cast<const short8v*>(
          (const char*)P_lds[w] + PBYTE(lcol, 64 + g * 16));
      __builtin_amdgcn_s_setprio(1);
      #pragma unroll
      for (int dt = 0; dt < 4; ++dt) {
        const int vrow = dt * 16 + lcol;
        const int vro = vrow * 128;
        short8v vf0 = *reinterpret_cast<const short8v*>(
            (const char*)V_lds[d] + vro + ((g ^ (vrow & 7)) << 4));
        short8v vf1 = *reinterpret_cast<const short8v*>(
            (const char*)V_lds[d] + vro + (((4 + g) ^ (vrow & 7)) << 4));
        o[m][dt] = __builtin_amdgcn_mfma_f32_16x16x32_bf16(pf0, vf0, o[m][dt], 0, 0, 0);
        o[m][dt] = __builtin_amdgcn_mfma_f32_16x16x32_bf16(pf1, vf1, o[m][dt], 0, 0, 0);
      }
      __builtin_amdgcn_s_setprio(0);
    }
  };

  if (qt == 0) {
    for (int kt = 0; kt < 2; ++kt) {
      STAGE(kt, 0);
      STAGE_KL(kt);
      MLOAD(kt, mv_cur);
      __syncthreads();
      COMPUTE(kt, 0, true, true);
      __syncthreads();
    }
  } else {
    const int ntiles = 2 * qt + 2;
    MLOAD(0, mv_cur);
    STAGE(0, 0);
    __syncthreads();
    for (int kt = 0; kt < ntiles; ++kt) {
      const int d = kt & 1;
      if (kt + 1 < ntiles) { STAGE(kt + 1, d ^ 1); MLOAD(kt + 1, mv_nxt); }
      COMPUTE(kt, d, compq, false);
      __syncthreads();
      #pragma unroll
      for (int c = 0; c < 4; ++c) mv_cur[c] = mv_nxt[c];
    }
  }

  #pragma unroll
  for (int m = 0; m < 2; ++m) {
    float inv[4];
    #pragma unroll
    for (int r = 0; r < 4; ++r) {
      float d = dsum[m][r];
      d += __shfl_xor(d, 1); d += __shfl_xor(d, 2);
      d += __shfl_xor(d, 4); d += __shfl_xor(d, 8);
      inv[r] = 1.0f / (d + 1e-9f);
    }
    ushort_t* ob = ao + ((size_t)b * Tn + qt * 128 + w * 32 + m * 16) * Cn + h * 64;
    #pragma unroll
    for (int dt = 0; dt < 4; ++dt)
      #pragma unroll
      for (int r = 0; r < 4; ++r)
        ob[(size_t)(g * 4 + r) * Cn + dt * 16 + lcol] = f2bf(o[m][dt][r] * inv[r]);
  }
}

extern "C" void kernel_launch(void* const* d_in, const int* in_sizes, int n_in,
                              void* d_out, int out_size, void* d_ws, size_t ws_size,
                              hipStream_t stream) {
  const float* x         = (const float*)d_in[0];
  const float* attn_mask = (const float*)d_in[1];
  const float* lambda    = (const float*)d_in[2];
  const float* W_attn    = (const float*)d_in[3];
  const float* W_proj    = (const float*)d_in[4];
  float* out = (float*)d_out;

  const size_t nBTC = (size_t)Bn * Tn * Cn;        // 6.29M
  const size_t nW1  = (size_t)Cn * 3 * Cn;         // 1.77M
  const size_t nW2  = (size_t)Cn * Cn;             // 0.59M
  ushort_t* xh  = (ushort_t*)d_ws;
  ushort_t* xl  = xh + nBTC;
  ushort_t* WhT = xl + nBTC;
  ushort_t* WlT = WhT + nW1;
  ushort_t* WpT = WlT + nW1;
  ushort_t* qh  = WpT + nW2;
  ushort_t* ql  = qh + nBTC;
  ushort_t* kh  = ql + nBTC;
  ushort_t* kl  = kh + nBTC;
  ushort_t* vt  = kl + nBTC;
  ushort_t* ao  = xh;   // xh dead after gemm1; reuse for attention output

  dim3 blk(256);

  conv_x_split<<<dim3((unsigned)(nBTC / 4 / 256)), blk, 0, stream>>>(
      x, xh, xl, (int)(nBTC / 4));
  conv_wT<1><<<dim3(36, 12), blk, 0, stream>>>(W_attn, WhT, WlT, Cn, 3 * Cn);
  conv_wT<0><<<dim3(12, 12), blk, 0, stream>>>(W_proj, WpT, nullptr, Cn, Cn);

  // full qkv: plain bf16 GEMM (hi only; v transposed)
  gemm_bf16<0, 1, 0, 0><<<dim3(18, 64), blk, 0, stream>>>(
      xh, nullptr, WhT, nullptr, Bn * Tn, 3 * Cn, Cn, 0, nullptr, lambda,
      qh, ql, kh, kl, vt);
  // accurate overwrite slice: rows t<256 of q,k (compensated, writes hi+lo)
  gemm_bf16<1, 1, 1, 1><<<dim3(12, 8), blk, 0, stream>>>(
      xh, xl, WhT, WlT, Bn * Tn, 3 * Cn, Cn, 0, nullptr, lambda,
      qh, ql, kh, kl, vt);

  attn_mfma<<<dim3(768), blk, 0, stream>>>(
      qh, ql, kh, kl, vt, attn_mask, ao);

  gemm_bf16<0, 0, 0, 0><<<dim3(6, 64), blk, 0, stream>>>(
      ao, nullptr, WpT, nullptr, Bn * Tn, Cn, Cn, 0, out, nullptr,
      nullptr, nullptr, nullptr, nullptr, nullptr);
}

// Round 11
// 193.466 us; speedup vs baseline: 2.3377x; 1.0277x over previous
//
#include <hip/hip_runtime.h>
#include <cstddef>
#include <cstdint>

#define Bn 4
#define Tn 2048
#define Cn 768
#define Hn 12

typedef __attribute__((ext_vector_type(8))) short short8v;
typedef __attribute__((ext_vector_type(4))) float f32x4;
typedef unsigned short ushort_t;

struct us4 { unsigned short x, y, z, w; };

__device__ inline unsigned short f2bf(float f) {
  union { float f; unsigned u; } v; v.f = f;
  unsigned r = v.u + 0x7FFFu + ((v.u >> 16) & 1u);
  return (unsigned short)(r >> 16);
}
__device__ inline float bf2f(unsigned short u) {
  union { unsigned u; float f; } v; v.u = ((unsigned)u) << 16;
  return v.f;
}
__device__ inline unsigned cvt_pk_bf16(float lo, float hi) {
  unsigned r;
  asm("v_cvt_pk_bf16_f32 %0, %1, %2" : "=v"(r) : "v"(lo), "v"(hi));
  return r;
}
__device__ inline float u2f(unsigned u) {
  union { unsigned u; float f; } v; v.u = u; return v.f;
}

#define GLOAD_LDS16(gp, lp)                                                        \
  __builtin_amdgcn_global_load_lds(                                                \
      (const __attribute__((address_space(1))) void*)(gp),                         \
      (__attribute__((address_space(3))) void*)(lp), 16, 0, 0)

// ---------------- x -> hi/lo bf16 split ----------------
__global__ __launch_bounds__(256) void conv_x_split(const float* __restrict__ in,
                                                    ushort_t* __restrict__ hi,
                                                    ushort_t* __restrict__ lo, int n4) {
  int i = blockIdx.x * 256 + threadIdx.x;
  if (i >= n4) return;
  float4 v = reinterpret_cast<const float4*>(in)[i];
  us4 h, l;
  h.x = f2bf(v.x); l.x = f2bf(v.x - bf2f(h.x));
  h.y = f2bf(v.y); l.y = f2bf(v.y - bf2f(h.y));
  h.z = f2bf(v.z); l.z = f2bf(v.z - bf2f(h.z));
  h.w = f2bf(v.w); l.w = f2bf(v.w - bf2f(h.w));
  reinterpret_cast<us4*>(hi)[i] = h;
  reinterpret_cast<us4*>(lo)[i] = l;
}

// ---------------- W[rows][cols] -> WT[cols][rows] bf16 (optionally hi+lo) --------
template <int SPLIT>
__global__ __launch_bounds__(256) void conv_wT(const float* __restrict__ W,
                                               ushort_t* __restrict__ WTh,
                                               ushort_t* __restrict__ WTl,
                                               int rows, int cols) {
  __shared__ float t[64][65];
  const int r0 = blockIdx.y * 64, c0 = blockIdx.x * 64;
  const int tid = threadIdx.x;
  const int c4 = (tid & 15) << 2;
  #pragma unroll
  for (int rr = 0; rr < 4; ++rr) {
    int r = rr * 16 + (tid >> 4);
    float4 v = *reinterpret_cast<const float4*>(&W[(size_t)(r0 + r) * cols + c0 + c4]);
    t[r][c4] = v.x; t[r][c4 + 1] = v.y; t[r][c4 + 2] = v.z; t[r][c4 + 3] = v.w;
  }
  __syncthreads();
  const int r4 = (tid & 15) << 2;
  #pragma unroll
  for (int cc = 0; cc < 4; ++cc) {
    int c = cc * 16 + (tid >> 4);
    float v0 = t[r4][c], v1 = t[r4 + 1][c], v2 = t[r4 + 2][c], v3 = t[r4 + 3][c];
    us4 h;
    h.x = f2bf(v0); h.y = f2bf(v1); h.z = f2bf(v2); h.w = f2bf(v3);
    *reinterpret_cast<us4*>(&WTh[(size_t)(c0 + c) * rows + r0 + r4]) = h;
    if (SPLIT) {
      us4 l;
      l.x = f2bf(v0 - bf2f(h.x)); l.y = f2bf(v1 - bf2f(h.y));
      l.z = f2bf(v2 - bf2f(h.z)); l.w = f2bf(v3 - bf2f(h.w));
      *reinterpret_cast<us4*>(&WTl[(size_t)(c0 + c) * rows + r0 + r4]) = l;
    }
  }
}

// ---------------- bf16 MFMA GEMM: C = A[M][K] @ Bt[N][K]^T, 128x128, BK=64 -------
// COMP=1: split-bf16 compensated (3-term MFMA, fp32 quality).
// MODE 0: C fp32.  MODE 1: fused qkv epilogue (q,k; v transposed).
// SLICE=1: bm = (y>>1)*Tn + (y&1)*128  (t<256 rows of each batch only).
// WLO=1: also store lo-parts of q,k.
template <int COMP, int MODE, int SLICE, int WLO>
__global__ __launch_bounds__(256) void gemm_bf16(
    const ushort_t* __restrict__ Ah, const ushort_t* __restrict__ Al,
    const ushort_t* __restrict__ Bh, const ushort_t* __restrict__ Bl,
    int M, int N, int K, int bn_off, float* __restrict__ C,
    const float* __restrict__ lambda,
    ushort_t* __restrict__ qhp, ushort_t* __restrict__ qlp,
    ushort_t* __restrict__ khp, ushort_t* __restrict__ klp,
    ushort_t* __restrict__ vtp) {
  __shared__ ushort_t As[COMP + 1][128 * 64];
  __shared__ ushort_t Bs[COMP + 1][128 * 64];

  const int tid = threadIdx.x;
  const int w = tid >> 6;
  const int lane = tid & 63;
  const int lcol = lane & 15;
  const int g = lane >> 4;
  const int bm = SLICE ? ((blockIdx.y >> 1) * Tn + (blockIdx.y & 1) * 128)
                       : (blockIdx.y * 128);
  const int bn = blockIdx.x * 128 + bn_off;
  const int wr = (w >> 1) * 64;
  const int wc = (w & 1) * 64;
  const int srow = tid >> 3;
  const int sslot = tid & 7;

  f32x4 acc[4][4];
  #pragma unroll
  for (int m = 0; m < 4; ++m)
    #pragma unroll
    for (int n = 0; n < 4; ++n)
      acc[m][n] = (f32x4){0.f, 0.f, 0.f, 0.f};

  for (int k0 = 0; k0 < K; k0 += 64) {
    __syncthreads();
    #pragma unroll
    for (int i = 0; i < 4; ++i) {
      const int row = i * 32 + srow;
      const int kslot = sslot ^ (row & 7);
      const size_t ga = (size_t)(bm + row) * K + k0 + kslot * 8;
      const size_t gb = (size_t)(bn + row) * K + k0 + kslot * 8;
      const size_t ldst = (size_t)(i * 256 + tid) * 16;
      GLOAD_LDS16(Ah + ga, (char*)As[0] + ldst);
      GLOAD_LDS16(Bh + gb, (char*)Bs[0] + ldst);
      if (COMP) {
        GLOAD_LDS16(Al + ga, (char*)As[COMP] + ldst);
        GLOAD_LDS16(Bl + gb, (char*)Bs[COMP] + ldst);
      }
    }
    __syncthreads();
    #pragma unroll
    for (int kk = 0; kk < 2; ++kk) {
      short8v a0[4], b0[4], a1[4], b1[4];
      #pragma unroll
      for (int m = 0; m < 4; ++m) {
        int row = wr + m * 16 + lcol;
        int off = row * 128 + (((kk * 4 + g) ^ (row & 7)) << 4);
        a0[m] = *reinterpret_cast<const short8v*>((const char*)As[0] + off);
        if (COMP) a1[m] = *reinterpret_cast<const short8v*>((const char*)As[COMP] + off);
      }
      #pragma unroll
      for (int n = 0; n < 4; ++n) {
        int row = wc + n * 16 + lcol;
        int off = row * 128 + (((kk * 4 + g) ^ (row & 7)) << 4);
        b0[n] = *reinterpret_cast<const short8v*>((const char*)Bs[0] + off);
        if (COMP) b1[n] = *reinterpret_cast<const short8v*>((const char*)Bs[COMP] + off);
      }
      #pragma unroll
      for (int m = 0; m < 4; ++m)
        #pragma unroll
        for (int n = 0; n < 4; ++n) {
          acc[m][n] = __builtin_amdgcn_mfma_f32_16x16x32_bf16(a0[m], b0[n], acc[m][n], 0, 0, 0);
          if (COMP) {
            acc[m][n] = __builtin_amdgcn_mfma_f32_16x16x32_bf16(a0[m], b1[n], acc[m][n], 0, 0, 0);
            acc[m][n] = __builtin_amdgcn_mfma_f32_16x16x32_bf16(a1[m], b0[n], acc[m][n], 0, 0, 0);
          }
        }
    }
  }

  if (MODE == 0) {
    #pragma unroll
    for (int m = 0; m < 4; ++m) {
      const int rowm = bm + wr + m * 16 + g * 4;
      #pragma unroll
      for (int n = 0; n < 4; ++n) {
        const int col = bn + wc + n * 16 + lcol;
        #pragma unroll
        for (int j = 0; j < 4; ++j)
          C[(size_t)(rowm + j) * N + col] = acc[m][n][j];
      }
    }
  } else {
    const int seg = bn / Cn;                  // uniform (768 % 128 == 0)
    const int nloc_base = bn - seg * Cn + wc;
    #pragma unroll
    for (int m = 0; m < 4; ++m) {
      const int mg = bm + wr + m * 16 + g * 4;
      const int bidx = mg >> 11;
      const int tbase = mg & (Tn - 1);
      float lgt[4];
      if (seg == 0) {
        #pragma unroll
        for (int j = 0; j < 4; ++j) lgt[j] = logf((float)(tbase + j) + 1.0f);
      }
      #pragma unroll
      for (int n = 0; n < 4; ++n) {
        const int nloc = nloc_base + n * 16 + lcol;
        const int h = nloc >> 6;
        const int d = nloc & 63;
        const size_t bhh = (size_t)(bidx * Hn + h);
        if (seg == 0) {
          const float lam = lambda[h];
          #pragma unroll
          for (int j = 0; j < 4; ++j) {
            float val = acc[m][n][j] * (0.125f * (1.0f + lam * lgt[j]));
            unsigned short hi = f2bf(val);
            size_t idx = (bhh * Tn + tbase + j) * 64 + d;
            qhp[idx] = hi;
            if (WLO) qlp[idx] = f2bf(val - bf2f(hi));
          }
        } else if (seg == 1) {
          #pragma unroll
          for (int j = 0; j < 4; ++j) {
            float val = acc[m][n][j];
            unsigned short hi = f2bf(val);
            size_t idx = (bhh * Tn + tbase + j) * 64 + d;
            khp[idx] = hi;
            if (WLO) klp[idx] = f2bf(val - bf2f(hi));
          }
        } else {
          #pragma unroll
          for (int j = 0; j < 4; ++j)
            vtp[(bhh * 64 + d) * Tn + tbase + j] = f2bf(acc[m][n][j]);
        }
      }
    }
  }
}

// ---------------- MFMA flash-style relu-attention, 64 q-rows/block ---------------
// qt in 0..31; grid 1536 = 6 complementary permutation slices (per-CU balance).
// LDS 40 KB -> 4 blocks/CU co-resident; 2-phase double-buffered K/V staging.
// Precision scoping (64-row tiles): qt<=1 q+k comp; qt<=3 q comp; else plain.
__global__ __launch_bounds__(256) void attn_mfma(
    const ushort_t* __restrict__ qh, const ushort_t* __restrict__ ql,
    const ushort_t* __restrict__ kh, const ushort_t* __restrict__ kl,
    const ushort_t* __restrict__ vt, const float* __restrict__ attn_mask,
    ushort_t* __restrict__ ao) {
  const int cc_ = blockIdx.x & 255;
  const int rr_ = blockIdx.x >> 8;           // 0..5
  const int bh  = (cc_ >> 5) + rr_ * 8;      // 0..47
  const int ii_ = cc_ & 31;
  int qt;
  switch (rr_) {
    case 0:  qt = ii_; break;
    case 1:  qt = 31 - ii_; break;
    case 2:  qt = (ii_ + 16) & 31; break;
    case 3:  qt = 31 - ((ii_ + 16) & 31); break;
    case 4:  qt = (ii_ + 8) & 31; break;
    default: qt = 31 - ((ii_ + 8) & 31); break;
  }
  const int b = bh / Hn, h = bh % Hn;
  const int tid = threadIdx.x;
  const int w = tid >> 6, lane = tid & 63, lcol = lane & 15, g = lane >> 4;

  const bool compq = (qt <= 3);   // q rows t<256

  __shared__ ushort_t Kh_lds[2][64 * 64];   // 16 KB (buffer 1 doubles as Kl for qt<=1)
  __shared__ ushort_t V_lds[2][64 * 64];    // 16 KB
  __shared__ ushort_t P_lds[4][16 * 64];    // 8 KB, per-wave, XOR-swizzled

  // Q hi fragments for the wave's 16 q-rows
  const size_t qoff0 = ((size_t)bh * Tn + qt * 64 + w * 16 + lcol) * 64;
  short8v qfh0 = *reinterpret_cast<const short8v*>(qh + qoff0 + g * 8);
  short8v qfh1 = *reinterpret_cast<const short8v*>(qh + qoff0 + 32 + g * 8);

  f32x4 o[4];
  float dsum[4];
  #pragma unroll
  for (int dt = 0; dt < 4; ++dt) o[dt] = (f32x4){0.f, 0.f, 0.f, 0.f};
  #pragma unroll
  for (int r = 0; r < 4; ++r) dsum[r] = 0.f;

  float mv_cur[4], mv_nxt[4];

  auto STAGE = [&](int kt, int d) {
    const ushort_t* ks = kh + ((size_t)bh * Tn + kt * 64) * 64;
    const ushort_t* vs = vt + (size_t)bh * 64 * Tn + kt * 64;
    #pragma unroll
    for (int it = 0; it < 2; ++it) {
      const int s = it * 256 + tid;
      const int row = s >> 3, sslot = s & 7;
      const int swz = (sslot ^ (row & 7)) * 8;
      GLOAD_LDS16(ks + row * 64 + swz, (char*)Kh_lds[d] + (size_t)s * 16);
      GLOAD_LDS16(vs + (size_t)row * Tn + swz, (char*)V_lds[d] + (size_t)s * 16);
    }
  };
  auto STAGE_KL = [&](int kt) {   // qt<=1 only: Kl parked in Kh_lds[1]
    const ushort_t* ls = kl + ((size_t)bh * Tn + kt * 64) * 64;
    #pragma unroll
    for (int it = 0; it < 2; ++it) {
      const int s = it * 256 + tid;
      const int row = s >> 3, sslot = s & 7;
      const int swz = (sslot ^ (row & 7)) * 8;
      GLOAD_LDS16(ls + row * 64 + swz, (char*)Kh_lds[1] + (size_t)s * 16);
    }
  };
  auto MLOAD = [&](int kt, float* mv) {
    #pragma unroll
    for (int c = 0; c < 4; ++c)
      mv[c] = attn_mask[b * Tn + kt * 64 + c * 16 + lcol];
  };

  // P byte offset with XOR swizzle (row-major [16][64] bf16, 128B rows)
  auto PBYTE = [](int row, int col2) { return row * 128 + (col2 ^ ((row & 7) << 4)); };

  auto COMPUTE = [&](int kt, int d, bool cq, bool ck) {
    const int qg = qt * 64 + w * 16;
    const bool diag = (kt == qt);
    short8v qfl0, qfl1;
    if (cq) {
      qfl0 = *reinterpret_cast<const short8v*>(ql + qoff0 + g * 8);
      qfl1 = *reinterpret_cast<const short8v*>(ql + qoff0 + 32 + g * 8);
    }
    #pragma unroll
    for (int c = 0; c < 4; ++c) {
      const int row = c * 16 + lcol;
      const int roff = row * 128;
      const int s0 = (g ^ (row & 7)) << 4;
      const int s1 = ((4 + g) ^ (row & 7)) << 4;
      short8v kf0 = *reinterpret_cast<const short8v*>((const char*)Kh_lds[d] + roff + s0);
      short8v kf1 = *reinterpret_cast<const short8v*>((const char*)Kh_lds[d] + roff + s1);
      f32x4 s = (f32x4){0.f, 0.f, 0.f, 0.f};
      __builtin_amdgcn_s_setprio(1);
      s = __builtin_amdgcn_mfma_f32_16x16x32_bf16(qfh0, kf0, s, 0, 0, 0);
      s = __builtin_amdgcn_mfma_f32_16x16x32_bf16(qfh1, kf1, s, 0, 0, 0);
      if (cq) {
        s = __builtin_amdgcn_mfma_f32_16x16x32_bf16(qfl0, kf0, s, 0, 0, 0);
        s = __builtin_amdgcn_mfma_f32_16x16x32_bf16(qfl1, kf1, s, 0, 0, 0);
      }
      if (ck) {
        short8v kl0 = *reinterpret_cast<const short8v*>((const char*)Kh_lds[1] + roff + s0);
        short8v kl1 = *reinterpret_cast<const short8v*>((const char*)Kh_lds[1] + roff + s1);
        s = __builtin_amdgcn_mfma_f32_16x16x32_bf16(qfh0, kl0, s, 0, 0, 0);
        s = __builtin_amdgcn_mfma_f32_16x16x32_bf16(qfh1, kl1, s, 0, 0, 0);
      }
      __builtin_amdgcn_s_setprio(0);
      const float mval = mv_cur[c];
      float sv[4];
      #pragma unroll
      for (int r = 0; r < 4; ++r) {
        float v = fmaxf(s[r], 0.f) * mval;
        if (diag) {
          const int kr = row;
          const int qr = w * 16 + g * 4 + r;
          v = (kr <= qr) ? v : 0.f;
        }
        sv[r] = v;
      }
      const unsigned p01 = cvt_pk_bf16(sv[0], sv[1]);
      const unsigned p23 = cvt_pk_bf16(sv[2], sv[3]);
      char* pb = (char*)P_lds[w];
      const int col2 = row * 2;   // k-col byte offset within P row
      *(ushort_t*)(pb + PBYTE(g * 4 + 0, col2)) = (ushort_t)p01;
      *(ushort_t*)(pb + PBYTE(g * 4 + 1, col2)) = (ushort_t)(p01 >> 16);
      *(ushort_t*)(pb + PBYTE(g * 4 + 2, col2)) = (ushort_t)p23;
      *(ushort_t*)(pb + PBYTE(g * 4 + 3, col2)) = (ushort_t)(p23 >> 16);
      dsum[0] += u2f(p01 << 16);
      dsum[1] += u2f(p01 & 0xFFFF0000u);
      dsum[2] += u2f(p23 << 16);
      dsum[3] += u2f(p23 & 0xFFFF0000u);
    }
    // PV (same-wave LDS ordering makes this safe; P region is wave-private)
    short8v pf0 = *reinterpret_cast<const short8v*>(
        (const char*)P_lds[w] + PBYTE(lcol, g * 16));
    short8v pf1 = *reinterpret_cast<const short8v*>(
        (const char*)P_lds[w] + PBYTE(lcol, 64 + g * 16));
    __builtin_amdgcn_s_setprio(1);
    #pragma unroll
    for (int dt = 0; dt < 4; ++dt) {
      const int vrow = dt * 16 + lcol;
      const int vro = vrow * 128;
      short8v vf0 = *reinterpret_cast<const short8v*>(
          (const char*)V_lds[d] + vro + ((g ^ (vrow & 7)) << 4));
      short8v vf1 = *reinterpret_cast<const short8v*>(
          (const char*)V_lds[d] + vro + (((4 + g) ^ (vrow & 7)) << 4));
      o[dt] = __builtin_amdgcn_mfma_f32_16x16x32_bf16(pf0, vf0, o[dt], 0, 0, 0);
      o[dt] = __builtin_amdgcn_mfma_f32_16x16x32_bf16(pf1, vf1, o[dt], 0, 0, 0);
    }
    __builtin_amdgcn_s_setprio(0);
  };

  if (qt <= 1) {
    // <=2 tiles, sequential, full q+k compensation (knife-edge rows t<128)
    for (int kt = 0; kt <= qt; ++kt) {
      STAGE(kt, 0);
      STAGE_KL(kt);
      MLOAD(kt, mv_cur);
      __syncthreads();
      COMPUTE(kt, 0, true, true);
      __syncthreads();
    }
  } else {
    const int ntiles = qt + 1;
    MLOAD(0, mv_cur);
    STAGE(0, 0);
    __syncthreads();
    for (int kt = 0; kt < ntiles; ++kt) {
      const int d = kt & 1;
      if (kt + 1 < ntiles) { STAGE(kt + 1, d ^ 1); MLOAD(kt + 1, mv_nxt); }
      COMPUTE(kt, d, compq, false);
      __syncthreads();
      #pragma unroll
      for (int c = 0; c < 4; ++c) mv_cur[c] = mv_nxt[c];
    }
  }

  float inv[4];
  #pragma unroll
  for (int r = 0; r < 4; ++r) {
    float d = dsum[r];
    d += __shfl_xor(d, 1); d += __shfl_xor(d, 2);
    d += __shfl_xor(d, 4); d += __shfl_xor(d, 8);
    inv[r] = 1.0f / (d + 1e-9f);
  }
  ushort_t* ob = ao + ((size_t)b * Tn + qt * 64 + w * 16) * Cn + h * 64;
  #pragma unroll
  for (int dt = 0; dt < 4; ++dt)
    #pragma unroll
    for (int r = 0; r < 4; ++r)
      ob[(size_t)(g * 4 + r) * Cn + dt * 16 + lcol] = f2bf(o[dt][r] * inv[r]);
}

extern "C" void kernel_launch(void* const* d_in, const int* in_sizes, int n_in,
                              void* d_out, int out_size, void* d_ws, size_t ws_size,
                              hipStream_t stream) {
  const float* x         = (const float*)d_in[0];
  const float* attn_mask = (const float*)d_in[1];
  const float* lambda    = (const float*)d_in[2];
  const float* W_attn    = (const float*)d_in[3];
  const float* W_proj    = (const float*)d_in[4];
  float* out = (float*)d_out;

  const size_t nBTC = (size_t)Bn * Tn * Cn;        // 6.29M
  const size_t nW1  = (size_t)Cn * 3 * Cn;         // 1.77M
  const size_t nW2  = (size_t)Cn * Cn;             // 0.59M
  ushort_t* xh  = (ushort_t*)d_ws;
  ushort_t* xl  = xh + nBTC;
  ushort_t* WhT = xl + nBTC;
  ushort_t* WlT = WhT + nW1;
  ushort_t* WpT = WlT + nW1;
  ushort_t* qh  = WpT + nW2;
  ushort_t* ql  = qh + nBTC;
  ushort_t* kh  = ql + nBTC;
  ushort_t* kl  = kh + nBTC;
  ushort_t* vt  = kl + nBTC;
  ushort_t* ao  = xh;   // xh dead after gemm1; reuse for attention output

  dim3 blk(256);

  conv_x_split<<<dim3((unsigned)(nBTC / 4 / 256)), blk, 0, stream>>>(
      x, xh, xl, (int)(nBTC / 4));
  conv_wT<1><<<dim3(36, 12), blk, 0, stream>>>(W_attn, WhT, WlT, Cn, 3 * Cn);
  conv_wT<0><<<dim3(12, 12), blk, 0, stream>>>(W_proj, WpT, nullptr, Cn, Cn);

  // full qkv: plain bf16 GEMM (hi only; v transposed)
  gemm_bf16<0, 1, 0, 0><<<dim3(18, 64), blk, 0, stream>>>(
      xh, nullptr, WhT, nullptr, Bn * Tn, 3 * Cn, Cn, 0, nullptr, lambda,
      qh, ql, kh, kl, vt);
  // accurate overwrite slice: rows t<256 of q,k (compensated, writes hi+lo)
  gemm_bf16<1, 1, 1, 1><<<dim3(12, 8), blk, 0, stream>>>(
      xh, xl, WhT, WlT, Bn * Tn, 3 * Cn, Cn, 0, nullptr, lambda,
      qh, ql, kh, kl, vt);

  attn_mfma<<<dim3(1536), blk, 0, stream>>>(
      qh, ql, kh, kl, vt, attn_mask, ao);

  gemm_bf16<0, 0, 0, 0><<<dim3(6, 64), blk, 0, stream>>>(
      ao, nullptr, WpT, nullptr, Bn * Tn, Cn, Cn, 0, out, nullptr,
      nullptr, nullptr, nullptr, nullptr, nullptr);
}

// Round 12
// 186.832 us; speedup vs baseline: 2.4207x; 1.0355x over previous
//
#include <hip/hip_runtime.h>
#include <cstddef>
#include <cstdint>

#define Bn 4
#define Tn 2048
#define Cn 768
#define Hn 12

typedef __attribute__((ext_vector_type(8))) short short8v;
typedef __attribute__((ext_vector_type(4))) float f32x4;
typedef unsigned short ushort_t;

struct us4 { unsigned short x, y, z, w; };

__device__ inline unsigned short f2bf(float f) {
  union { float f; unsigned u; } v; v.f = f;
  unsigned r = v.u + 0x7FFFu + ((v.u >> 16) & 1u);
  return (unsigned short)(r >> 16);
}
__device__ inline float bf2f(unsigned short u) {
  union { unsigned u; float f; } v; v.u = ((unsigned)u) << 16;
  return v.f;
}
__device__ inline unsigned cvt_pk_bf16(float lo, float hi) {
  unsigned r;
  asm("v_cvt_pk_bf16_f32 %0, %1, %2" : "=v"(r) : "v"(lo), "v"(hi));
  return r;
}
__device__ inline float u2f(unsigned u) {
  union { unsigned u; float f; } v; v.u = u; return v.f;
}

#define GLOAD_LDS16(gp, lp)                                                        \
  __builtin_amdgcn_global_load_lds(                                                \
      (const __attribute__((address_space(1))) void*)(gp),                         \
      (__attribute__((address_space(3))) void*)(lp), 16, 0, 0)

// ---------------- x -> hi/lo bf16 split ----------------
__global__ __launch_bounds__(256) void conv_x_split(const float* __restrict__ in,
                                                    ushort_t* __restrict__ hi,
                                                    ushort_t* __restrict__ lo, int n4) {
  int i = blockIdx.x * 256 + threadIdx.x;
  if (i >= n4) return;
  float4 v = reinterpret_cast<const float4*>(in)[i];
  us4 h, l;
  h.x = f2bf(v.x); l.x = f2bf(v.x - bf2f(h.x));
  h.y = f2bf(v.y); l.y = f2bf(v.y - bf2f(h.y));
  h.z = f2bf(v.z); l.z = f2bf(v.z - bf2f(h.z));
  h.w = f2bf(v.w); l.w = f2bf(v.w - bf2f(h.w));
  reinterpret_cast<us4*>(hi)[i] = h;
  reinterpret_cast<us4*>(lo)[i] = l;
}

// ---------------- W[rows][cols] -> WT[cols][rows] bf16 (optionally hi+lo) --------
template <int SPLIT>
__global__ __launch_bounds__(256) void conv_wT(const float* __restrict__ W,
                                               ushort_t* __restrict__ WTh,
                                               ushort_t* __restrict__ WTl,
                                               int rows, int cols) {
  __shared__ float t[64][65];
  const int r0 = blockIdx.y * 64, c0 = blockIdx.x * 64;
  const int tid = threadIdx.x;
  const int c4 = (tid & 15) << 2;
  #pragma unroll
  for (int rr = 0; rr < 4; ++rr) {
    int r = rr * 16 + (tid >> 4);
    float4 v = *reinterpret_cast<const float4*>(&W[(size_t)(r0 + r) * cols + c0 + c4]);
    t[r][c4] = v.x; t[r][c4 + 1] = v.y; t[r][c4 + 2] = v.z; t[r][c4 + 3] = v.w;
  }
  __syncthreads();
  const int r4 = (tid & 15) << 2;
  #pragma unroll
  for (int cc = 0; cc < 4; ++cc) {
    int c = cc * 16 + (tid >> 4);
    float v0 = t[r4][c], v1 = t[r4 + 1][c], v2 = t[r4 + 2][c], v3 = t[r4 + 3][c];
    us4 h;
    h.x = f2bf(v0); h.y = f2bf(v1); h.z = f2bf(v2); h.w = f2bf(v3);
    *reinterpret_cast<us4*>(&WTh[(size_t)(c0 + c) * rows + r0 + r4]) = h;
    if (SPLIT) {
      us4 l;
      l.x = f2bf(v0 - bf2f(h.x)); l.y = f2bf(v1 - bf2f(h.y));
      l.z = f2bf(v2 - bf2f(h.z)); l.w = f2bf(v3 - bf2f(h.w));
      *reinterpret_cast<us4*>(&WTl[(size_t)(c0 + c) * rows + r0 + r4]) = l;
    }
  }
}

// ---------------- bf16 MFMA GEMM: C = A[M][K] @ Bt[N][K]^T, 128x128, BK=64 -------
// COMP=1: split-bf16 compensated (3-term MFMA, fp32 quality).
// MODE 0: C fp32.  MODE 1: fused qkv epilogue (q,k; v transposed).
// SLICE=1: bm = (y>>1)*Tn + (y&1)*128  (t<256 rows of each batch only).
// WLO=1: also store lo-parts of q,k.
template <int COMP, int MODE, int SLICE, int WLO>
__global__ __launch_bounds__(256) void gemm_bf16(
    const ushort_t* __restrict__ Ah, const ushort_t* __restrict__ Al,
    const ushort_t* __restrict__ Bh, const ushort_t* __restrict__ Bl,
    int M, int N, int K, int bn_off, float* __restrict__ C,
    const float* __restrict__ lambda,
    ushort_t* __restrict__ qhp, ushort_t* __restrict__ qlp,
    ushort_t* __restrict__ khp, ushort_t* __restrict__ klp,
    ushort_t* __restrict__ vtp) {
  __shared__ ushort_t As[COMP + 1][128 * 64];
  __shared__ ushort_t Bs[COMP + 1][128 * 64];

  const int tid = threadIdx.x;
  const int w = tid >> 6;
  const int lane = tid & 63;
  const int lcol = lane & 15;
  const int g = lane >> 4;
  const int bm = SLICE ? ((blockIdx.y >> 1) * Tn + (blockIdx.y & 1) * 128)
                       : (blockIdx.y * 128);
  const int bn = blockIdx.x * 128 + bn_off;
  const int wr = (w >> 1) * 64;
  const int wc = (w & 1) * 64;
  const int srow = tid >> 3;
  const int sslot = tid & 7;

  f32x4 acc[4][4];
  #pragma unroll
  for (int m = 0; m < 4; ++m)
    #pragma unroll
    for (int n = 0; n < 4; ++n)
      acc[m][n] = (f32x4){0.f, 0.f, 0.f, 0.f};

  for (int k0 = 0; k0 < K; k0 += 64) {
    __syncthreads();
    #pragma unroll
    for (int i = 0; i < 4; ++i) {
      const int row = i * 32 + srow;
      const int kslot = sslot ^ (row & 7);
      const size_t ga = (size_t)(bm + row) * K + k0 + kslot * 8;
      const size_t gb = (size_t)(bn + row) * K + k0 + kslot * 8;
      const size_t ldst = (size_t)(i * 256 + tid) * 16;
      GLOAD_LDS16(Ah + ga, (char*)As[0] + ldst);
      GLOAD_LDS16(Bh + gb, (char*)Bs[0] + ldst);
      if (COMP) {
        GLOAD_LDS16(Al + ga, (char*)As[COMP] + ldst);
        GLOAD_LDS16(Bl + gb, (char*)Bs[COMP] + ldst);
      }
    }
    __syncthreads();
    #pragma unroll
    for (int kk = 0; kk < 2; ++kk) {
      short8v a0[4], b0[4], a1[4], b1[4];
      #pragma unroll
      for (int m = 0; m < 4; ++m) {
        int row = wr + m * 16 + lcol;
        int off = row * 128 + (((kk * 4 + g) ^ (row & 7)) << 4);
        a0[m] = *reinterpret_cast<const short8v*>((const char*)As[0] + off);
        if (COMP) a1[m] = *reinterpret_cast<const short8v*>((const char*)As[COMP] + off);
      }
      #pragma unroll
      for (int n = 0; n < 4; ++n) {
        int row = wc + n * 16 + lcol;
        int off = row * 128 + (((kk * 4 + g) ^ (row & 7)) << 4);
        b0[n] = *reinterpret_cast<const short8v*>((const char*)Bs[0] + off);
        if (COMP) b1[n] = *reinterpret_cast<const short8v*>((const char*)Bs[COMP] + off);
      }
      #pragma unroll
      for (int m = 0; m < 4; ++m)
        #pragma unroll
        for (int n = 0; n < 4; ++n) {
          acc[m][n] = __builtin_amdgcn_mfma_f32_16x16x32_bf16(a0[m], b0[n], acc[m][n], 0, 0, 0);
          if (COMP) {
            acc[m][n] = __builtin_amdgcn_mfma_f32_16x16x32_bf16(a0[m], b1[n], acc[m][n], 0, 0, 0);
            acc[m][n] = __builtin_amdgcn_mfma_f32_16x16x32_bf16(a1[m], b0[n], acc[m][n], 0, 0, 0);
          }
        }
    }
  }

  if (MODE == 0) {
    #pragma unroll
    for (int m = 0; m < 4; ++m) {
      const int rowm = bm + wr + m * 16 + g * 4;
      #pragma unroll
      for (int n = 0; n < 4; ++n) {
        const int col = bn + wc + n * 16 + lcol;
        #pragma unroll
        for (int j = 0; j < 4; ++j)
          C[(size_t)(rowm + j) * N + col] = acc[m][n][j];
      }
    }
  } else {
    const int seg = bn / Cn;                  // uniform (768 % 128 == 0)
    const int nloc_base = bn - seg * Cn + wc;
    #pragma unroll
    for (int m = 0; m < 4; ++m) {
      const int mg = bm + wr + m * 16 + g * 4;
      const int bidx = mg >> 11;
      const int tbase = mg & (Tn - 1);
      float lgt[4];
      if (seg == 0) {
        #pragma unroll
        for (int j = 0; j < 4; ++j) lgt[j] = logf((float)(tbase + j) + 1.0f);
      }
      #pragma unroll
      for (int n = 0; n < 4; ++n) {
        const int nloc = nloc_base + n * 16 + lcol;
        const int h = nloc >> 6;
        const int d = nloc & 63;
        const size_t bhh = (size_t)(bidx * Hn + h);
        if (seg == 0) {
          const float lam = lambda[h];
          #pragma unroll
          for (int j = 0; j < 4; ++j) {
            float val = acc[m][n][j] * (0.125f * (1.0f + lam * lgt[j]));
            unsigned short hi = f2bf(val);
            size_t idx = (bhh * Tn + tbase + j) * 64 + d;
            qhp[idx] = hi;
            if (WLO) qlp[idx] = f2bf(val - bf2f(hi));
          }
        } else if (seg == 1) {
          #pragma unroll
          for (int j = 0; j < 4; ++j) {
            float val = acc[m][n][j];
            unsigned short hi = f2bf(val);
            size_t idx = (bhh * Tn + tbase + j) * 64 + d;
            khp[idx] = hi;
            if (WLO) klp[idx] = f2bf(val - bf2f(hi));
          }
        } else {
          #pragma unroll
          for (int j = 0; j < 4; ++j)
            vtp[(bhh * 64 + d) * Tn + tbase + j] = f2bf(acc[m][n][j]);
        }
      }
    }
  }
}

// ---------------- MFMA flash-style relu-attention, 64 q-rows/block ---------------
// Swapped QK^T: s2 = mfma(K,Q) = S^T[k][q] -> lane holds 4 consecutive k for one q
// -> P written as ONE ds_write_b64 per c-iter; dsum is scalar per lane.
// XCD-aware mapping: blockIdx&7 = XCD, each XCD owns 6 bh (K/V set 3MB < 4MB L2).
// LDS 40 KB; 2-phase double-buffered K/V staging.
// Precision scoping (64-row tiles): qt<=1 q+k comp; qt<=3 q comp; else plain.
__global__ __launch_bounds__(256) void attn_mfma(
    const ushort_t* __restrict__ qh, const ushort_t* __restrict__ ql,
    const ushort_t* __restrict__ kh, const ushort_t* __restrict__ kl,
    const ushort_t* __restrict__ vt, const float* __restrict__ attn_mask,
    ushort_t* __restrict__ ao) {
  const int xcd = blockIdx.x & 7;
  const int idx = blockIdx.x >> 3;           // 0..191
  const int bh  = xcd * 6 + (idx % 6);       // 0..47
  const int tt  = idx / 6;                   // 0..31
  const int qt  = (tt & 1) ? (31 - (tt >> 1)) : (tt >> 1);
  const int b = bh / Hn, h = bh % Hn;
  const int tid = threadIdx.x;
  const int w = tid >> 6, lane = tid & 63, lcol = lane & 15, g = lane >> 4;

  const bool compq = (qt <= 3);   // q rows t<256

  __shared__ ushort_t Kh_lds[2][64 * 64];   // 16 KB (buffer 1 doubles as Kl for qt<=1)
  __shared__ ushort_t V_lds[2][64 * 64];    // 16 KB
  __shared__ ushort_t P_lds[4][16 * 64];    // 8 KB, per-wave [16 q][64 k], XOR-swz

  // Q hi fragments for the wave's 16 q-rows
  const size_t qoff0 = ((size_t)bh * Tn + qt * 64 + w * 16 + lcol) * 64;
  short8v qfh0 = *reinterpret_cast<const short8v*>(qh + qoff0 + g * 8);
  short8v qfh1 = *reinterpret_cast<const short8v*>(qh + qoff0 + 32 + g * 8);

  f32x4 o[4];
  #pragma unroll
  for (int dt = 0; dt < 4; ++dt) o[dt] = (f32x4){0.f, 0.f, 0.f, 0.f};
  float dsum = 0.f;

  auto STAGE = [&](int kt, int d) {
    const ushort_t* ks = kh + ((size_t)bh * Tn + kt * 64) * 64;
    const ushort_t* vs = vt + (size_t)bh * 64 * Tn + kt * 64;
    #pragma unroll
    for (int it = 0; it < 2; ++it) {
      const int s = it * 256 + tid;
      const int row = s >> 3, sslot = s & 7;
      const int swz = (sslot ^ (row & 7)) * 8;
      GLOAD_LDS16(ks + row * 64 + swz, (char*)Kh_lds[d] + (size_t)s * 16);
      GLOAD_LDS16(vs + (size_t)row * Tn + swz, (char*)V_lds[d] + (size_t)s * 16);
    }
  };
  auto STAGE_KL = [&](int kt) {   // qt<=1 only: Kl parked in Kh_lds[1]
    const ushort_t* ls = kl + ((size_t)bh * Tn + kt * 64) * 64;
    #pragma unroll
    for (int it = 0; it < 2; ++it) {
      const int s = it * 256 + tid;
      const int row = s >> 3, sslot = s & 7;
      const int swz = (sslot ^ (row & 7)) * 8;
      GLOAD_LDS16(ls + row * 64 + swz, (char*)Kh_lds[1] + (size_t)s * 16);
    }
  };

  auto COMPUTE = [&](int kt, int d, bool cq, bool ck) {
    // mask: 4 consecutive k-values per lane (k = c*16 + g*4 + r)
    float4 mv4[4];
    #pragma unroll
    for (int c = 0; c < 4; ++c)
      mv4[c] = *reinterpret_cast<const float4*>(
          &attn_mask[b * Tn + kt * 64 + c * 16 + g * 4]);
    const bool diag = (kt == qt);
    const int qr = qt * 64 + w * 16 + lcol;
    short8v qfl0, qfl1;
    if (cq) {
      qfl0 = *reinterpret_cast<const short8v*>(ql + qoff0 + g * 8);
      qfl1 = *reinterpret_cast<const short8v*>(ql + qoff0 + 32 + g * 8);
    }
    char* pb = (char*)P_lds[w];
    const int pswz = (lcol & 7) << 4;
    #pragma unroll
    for (int c = 0; c < 4; ++c) {
      const int row = c * 16 + lcol;
      const int roff = row * 128;
      const int s0 = (g ^ (row & 7)) << 4;
      const int s1 = ((4 + g) ^ (row & 7)) << 4;
      short8v kf0 = *reinterpret_cast<const short8v*>((const char*)Kh_lds[d] + roff + s0);
      short8v kf1 = *reinterpret_cast<const short8v*>((const char*)Kh_lds[d] + roff + s1);
      f32x4 s = (f32x4){0.f, 0.f, 0.f, 0.f};
      __builtin_amdgcn_s_setprio(1);
      s = __builtin_amdgcn_mfma_f32_16x16x32_bf16(kf0, qfh0, s, 0, 0, 0);
      s = __builtin_amdgcn_mfma_f32_16x16x32_bf16(kf1, qfh1, s, 0, 0, 0);
      if (cq) {
        s = __builtin_amdgcn_mfma_f32_16x16x32_bf16(kf0, qfl0, s, 0, 0, 0);
        s = __builtin_amdgcn_mfma_f32_16x16x32_bf16(kf1, qfl1, s, 0, 0, 0);
      }
      if (ck) {
        short8v kl0 = *reinterpret_cast<const short8v*>((const char*)Kh_lds[1] + roff + s0);
        short8v kl1 = *reinterpret_cast<const short8v*>((const char*)Kh_lds[1] + roff + s1);
        s = __builtin_amdgcn_mfma_f32_16x16x32_bf16(kl0, qfh0, s, 0, 0, 0);
        s = __builtin_amdgcn_mfma_f32_16x16x32_bf16(kl1, qfh1, s, 0, 0, 0);
      }
      __builtin_amdgcn_s_setprio(0);
      // lane holds S^T[k = kt*64 + c*16 + g*4 + r][q = qr]
      const float* mvp = &mv4[c].x;
      float sv[4];
      #pragma unroll
      for (int r = 0; r < 4; ++r) {
        float v = fmaxf(s[r], 0.f) * mvp[r];
        if (diag) {
          const int kr = kt * 64 + c * 16 + g * 4 + r;
          v = (kr <= qr) ? v : 0.f;
        }
        sv[r] = v;
      }
      const unsigned p01 = cvt_pk_bf16(sv[0], sv[1]);
      const unsigned p23 = cvt_pk_bf16(sv[2], sv[3]);
      // one b64 write: P[q=lcol][k = c*16+g*4 .. +3]
      *reinterpret_cast<uint2*>(pb + lcol * 128 + ((c * 32 + g * 8) ^ pswz)) =
          make_uint2(p01, p23);
      dsum += u2f(p01 << 16);
      dsum += u2f(p01 & 0xFFFF0000u);
      dsum += u2f(p23 << 16);
      dsum += u2f(p23 & 0xFFFF0000u);
    }
    // PV (same-wave LDS ordering; P region is wave-private)
    short8v pf0 = *reinterpret_cast<const short8v*>(pb + lcol * 128 + ((g * 16) ^ pswz));
    short8v pf1 = *reinterpret_cast<const short8v*>(pb + lcol * 128 + ((64 + g * 16) ^ pswz));
    __builtin_amdgcn_s_setprio(1);
    #pragma unroll
    for (int dt = 0; dt < 4; ++dt) {
      const int vrow = dt * 16 + lcol;
      const int vro = vrow * 128;
      short8v vf0 = *reinterpret_cast<const short8v*>(
          (const char*)V_lds[d] + vro + ((g ^ (vrow & 7)) << 4));
      short8v vf1 = *reinterpret_cast<const short8v*>(
          (const char*)V_lds[d] + vro + (((4 + g) ^ (vrow & 7)) << 4));
      o[dt] = __builtin_amdgcn_mfma_f32_16x16x32_bf16(pf0, vf0, o[dt], 0, 0, 0);
      o[dt] = __builtin_amdgcn_mfma_f32_16x16x32_bf16(pf1, vf1, o[dt], 0, 0, 0);
    }
    __builtin_amdgcn_s_setprio(0);
  };

  if (qt <= 1) {
    // <=2 tiles, sequential, full q+k compensation (knife-edge rows t<128)
    for (int kt = 0; kt <= qt; ++kt) {
      STAGE(kt, 0);
      STAGE_KL(kt);
      __syncthreads();
      COMPUTE(kt, 0, true, true);
      __syncthreads();
    }
  } else {
    const int ntiles = qt + 1;
    STAGE(0, 0);
    __syncthreads();
    for (int kt = 0; kt < ntiles; ++kt) {
      const int d = kt & 1;
      if (kt + 1 < ntiles) STAGE(kt + 1, d ^ 1);
      COMPUTE(kt, d, compq, false);
      __syncthreads();
    }
  }

  // dsum holds partial den for q=lcol (this lane's k-slices); reduce over g.
  float dtot = dsum;
  dtot += __shfl_xor(dtot, 16);
  dtot += __shfl_xor(dtot, 32);
  const float invq = 1.0f / (dtot + 1e-9f);
  float invs[4];
  #pragma unroll
  for (int r = 0; r < 4; ++r) invs[r] = __shfl(invq, g * 4 + r);

  ushort_t* ob = ao + ((size_t)b * Tn + qt * 64 + w * 16) * Cn + h * 64;
  #pragma unroll
  for (int dt = 0; dt < 4; ++dt)
    #pragma unroll
    for (int r = 0; r < 4; ++r)
      ob[(size_t)(g * 4 + r) * Cn + dt * 16 + lcol] = f2bf(o[dt][r] * invs[r]);
}

extern "C" void kernel_launch(void* const* d_in, const int* in_sizes, int n_in,
                              void* d_out, int out_size, void* d_ws, size_t ws_size,
                              hipStream_t stream) {
  const float* x         = (const float*)d_in[0];
  const float* attn_mask = (const float*)d_in[1];
  const float* lambda    = (const float*)d_in[2];
  const float* W_attn    = (const float*)d_in[3];
  const float* W_proj    = (const float*)d_in[4];
  float* out = (float*)d_out;

  const size_t nBTC = (size_t)Bn * Tn * Cn;        // 6.29M
  const size_t nW1  = (size_t)Cn * 3 * Cn;         // 1.77M
  const size_t nW2  = (size_t)Cn * Cn;             // 0.59M
  ushort_t* xh  = (ushort_t*)d_ws;
  ushort_t* xl  = xh + nBTC;
  ushort_t* WhT = xl + nBTC;
  ushort_t* WlT = WhT + nW1;
  ushort_t* WpT = WlT + nW1;
  ushort_t* qh  = WpT + nW2;
  ushort_t* ql  = qh + nBTC;
  ushort_t* kh  = ql + nBTC;
  ushort_t* kl  = kh + nBTC;
  ushort_t* vt  = kl + nBTC;
  ushort_t* ao  = xh;   // xh dead after gemm1; reuse for attention output

  dim3 blk(256);

  conv_x_split<<<dim3((unsigned)(nBTC / 4 / 256)), blk, 0, stream>>>(
      x, xh, xl, (int)(nBTC / 4));
  conv_wT<1><<<dim3(36, 12), blk, 0, stream>>>(W_attn, WhT, WlT, Cn, 3 * Cn);
  conv_wT<0><<<dim3(12, 12), blk, 0, stream>>>(W_proj, WpT, nullptr, Cn, Cn);

  // full qkv: plain bf16 GEMM (hi only; v transposed)
  gemm_bf16<0, 1, 0, 0><<<dim3(18, 64), blk, 0, stream>>>(
      xh, nullptr, WhT, nullptr, Bn * Tn, 3 * Cn, Cn, 0, nullptr, lambda,
      qh, ql, kh, kl, vt);
  // accurate overwrite slice: rows t<256 of q,k (compensated, writes hi+lo)
  gemm_bf16<1, 1, 1, 1><<<dim3(12, 8), blk, 0, stream>>>(
      xh, xl, WhT, WlT, Bn * Tn, 3 * Cn, Cn, 0, nullptr, lambda,
      qh, ql, kh, kl, vt);

  attn_mfma<<<dim3(1536), blk, 0, stream>>>(
      qh, ql, kh, kl, vt, attn_mask, ao);

  gemm_bf16<0, 0, 0, 0><<<dim3(6, 64), blk, 0, stream>>>(
      ao, nullptr, WpT, nullptr, Bn * Tn, Cn, Cn, 0, out, nullptr,
      nullptr, nullptr, nullptr, nullptr, nullptr);
}